// Round 12
// baseline (2351.289 us; speedup 1.0000x reference)
//
#include <hip/hip_runtime.h>
#include <hip/hip_bf16.h>
#include <float.h>

#define NEG_SLOPE 0.01f

typedef float v2f __attribute__((ext_vector_type(2)));

__device__ __forceinline__ float leaky(float x){ return x >= 0.0f ? x : NEG_SLOPE * x; }

#if !__has_builtin(__builtin_elementwise_fma)
#error "need __builtin_elementwise_fma"
#endif

#define RPT16(M) M(0) M(1) M(2) M(3) M(4) M(5) M(6) M(7) \
                 M(8) M(9) M(10) M(11) M(12) M(13) M(14) M(15)
#define RPT8(M) M(0) M(1) M(2) M(3) M(4) M(5) M(6) M(7)

// ---------------- all 28 weight matrices [o][d] -> [d][o], one launch ----------------
// dst layout: [0,1]=fn_wc, [2,3]=fn_wg, [4..15]=res_wc, [16..27]=res_wg
__global__ void k_transpose_all(const float* __restrict__ a, const float* __restrict__ b2,
                                const float* __restrict__ c, const float* __restrict__ d,
                                float* __restrict__ dst){
    int m = blockIdx.x;
    const float* s;
    if (m < 2) s = a + (size_t)m * 4096;
    else if (m < 4) s = b2 + (size_t)(m - 2) * 4096;
    else if (m < 16) s = c + (size_t)(m - 4) * 4096;
    else s = d + (size_t)(m - 16) * 4096;
    float* o = dst + (size_t)m * 4096;
    for (int t = threadIdx.x; t < 4096; t += blockDim.x){
        int oo = t >> 6, dd = t & 63;
        o[dd * 64 + oo] = s[t];
    }
}

// ---------------- first conv 3->64, dual-write dm + pm ----------------
__global__ void __launch_bounds__(256, 1)
k_conv0(const float* __restrict__ xyz, const float* __restrict__ w0,
        float* __restrict__ dm, float* __restrict__ pm, int n){
    int b = blockIdx.y;
    int lane = threadIdx.x & 63;
    int w = threadIdx.x >> 6;
    int j = blockIdx.x * 64 + lane;
    const float* X = xyz + (size_t)b * 3 * n;
    float x = X[j], y = X[n + j], z = X[2 * n + j];
    float* PO = pm + ((size_t)b * n + j) * 64 + w * 16;
    #pragma unroll
    for (int c = 0; c < 16; ++c){
        int oo = w * 16 + c;
        float v = w0[oo*3] * x + w0[oo*3+1] * y + w0[oo*3+2] * z;
        dm[((size_t)b * 64 + oo) * n + j] = v;
        PO[c] = v;
    }
}

// ---------------- kNN helpers ----------------
#define KNN_CHUNK 1024
#define BKNN 256

#define KNN_INS(bdX, biX) { bool c = cd < bdX; float tf = bdX; int ti = biX; \
    bdX = c ? cd : bdX; biX = c ? ci : biX; cd = c ? tf : cd; ci = c ? ti : ci; }

#define KNN_PROC(r, jj) { \
    float dot = qx * r.x + qy * r.y + qz * r.z; \
    float dcur = qq + r.w - 2.0f * dot; \
    if (dcur < bd7){ \
        float cd = dcur; int ci = (jj); \
        KNN_INS(bd0, bi0); KNN_INS(bd1, bi1); KNN_INS(bd2, bi2); KNN_INS(bd3, bi3); \
        KNN_INS(bd4, bi4); KNN_INS(bd5, bi5); KNN_INS(bd6, bi6); KNN_INS(bd7, bi7); \
    } }

// top-8 over an LDS float4 array (r.w = |r|^2), ascending j + strict '<' tie-break
#define KNN8(REFS, NR, QV, OROW) { \
    float qx = (QV).x, qy = (QV).y, qz = (QV).z; \
    float qq = qx*qx + qy*qy + qz*qz; \
    float bd0=FLT_MAX,bd1=FLT_MAX,bd2=FLT_MAX,bd3=FLT_MAX; \
    float bd4=FLT_MAX,bd5=FLT_MAX,bd6=FLT_MAX,bd7=FLT_MAX; \
    int bi0=0,bi1=0,bi2=0,bi3=0,bi4=0,bi5=0,bi6=0,bi7=0; \
    for (int j_ = 0; j_ < (NR); ++j_){ \
        float4 r = (REFS)[j_]; \
        KNN_PROC(r, j_) \
    } \
    (OROW)[0]=bi0; (OROW)[1]=bi1; (OROW)[2]=bi2; (OROW)[3]=bi3; \
    (OROW)[4]=bi4; (OROW)[5]=bi5; (OROW)[6]=bi6; (OROW)[7]=bi7; }

__global__ void __launch_bounds__(BKNN, 2)
k_knn(const float* __restrict__ q, const float* __restrict__ ref,
      int M, int Nr, int* __restrict__ idx_out){
    __shared__ float4 sref[KNN_CHUNK];
    int b = blockIdx.y;
    int m = blockIdx.x * BKNN + threadIdx.x;
    const float* Q = q + (size_t)b * 3 * M;
    const float* R = ref + (size_t)b * 3 * Nr;
    bool valid = (m < M);
    float qx = 0.f, qy = 0.f, qz = 0.f, qq = 0.f;
    if (valid){
        qx = Q[m]; qy = Q[M + m]; qz = Q[2 * M + m];
        qq = qx*qx + qy*qy + qz*qz;
    }
    float bd0 = FLT_MAX, bd1 = FLT_MAX, bd2 = FLT_MAX, bd3 = FLT_MAX;
    float bd4 = FLT_MAX, bd5 = FLT_MAX, bd6 = FLT_MAX, bd7 = FLT_MAX;
    int bi0 = 0, bi1 = 0, bi2 = 0, bi3 = 0, bi4 = 0, bi5 = 0, bi6 = 0, bi7 = 0;

    for (int base = 0; base < Nr; base += KNN_CHUNK){
        int jmax = min(KNN_CHUNK, Nr - base);
        for (int j = threadIdx.x; j < jmax; j += BKNN){
            float rx = R[base + j], ry = R[Nr + base + j], rz = R[2 * Nr + base + j];
            sref[j] = make_float4(rx, ry, rz, rx*rx + ry*ry + rz*rz);
        }
        __syncthreads();
        for (int j = 0; j < jmax; j += 4){
            float4 r0 = sref[j+0]; float4 r1 = sref[j+1];
            float4 r2 = sref[j+2]; float4 r3 = sref[j+3];
            KNN_PROC(r0, base + j + 0)
            KNN_PROC(r1, base + j + 1)
            KNN_PROC(r2, base + j + 2)
            KNN_PROC(r3, base + j + 3)
        }
        __syncthreads();
    }
    if (valid){
        int* o = idx_out + ((size_t)b * M + m) * 8;
        o[0] = bi0; o[1] = bi1; o[2] = bi2; o[3] = bi3;
        o[4] = bi4; o[5] = bi5; o[6] = bi6; o[7] = bi7;
    }
}

// ---------------- FPS primitives ----------------
template<int CTRL>
__device__ __forceinline__ void dpp2(unsigned long long &bp){
    unsigned h = (unsigned)(bp >> 32), l = (unsigned)bp;
    unsigned th = (unsigned)__builtin_amdgcn_update_dpp(0, (int)h, CTRL, 0xF, 0xF, true);
    unsigned tl = (unsigned)__builtin_amdgcn_update_dpp(0, (int)l, CTRL, 0xF, 0xF, true);
    unsigned long long tp = ((unsigned long long)th << 32) | tl;
    bp = tp > bp ? tp : bp;
}
#define DPP_REDUCE2(bp) dpp2<0x111>(bp); dpp2<0x112>(bp); dpp2<0x114>(bp); \
    dpp2<0x118>(bp); dpp2<0x142>(bp); dpp2<0x143>(bp);

#define FPS_DECL(i) v2f px##i, py##i, pz##i, ds##i;
#define FPS_LOAD(i) { int g0 = tid + (2*(i))*T, g1 = g0 + T; \
    px##i = (v2f){X[g0], X[g1]}; py##i = (v2f){X[N+g0], X[N+g1]}; \
    pz##i = (v2f){X[2*N+g0], X[2*N+g1]}; ds##i = (v2f){1e10f, 1e10f}; }
#define FPS_PIN(i) asm volatile("" : "+v"(px##i), "+v"(py##i), "+v"(pz##i));
// dist >= 0 => float bit order == value order; ~gi larger => gi smaller, so
// u64 max == (dist >, tie: idx <) exactly.
#define FPS_UPD(i) { \
    v2f dx = px##i - l2x, dy = py##i - l2y, dz = pz##i - l2z; \
    v2f dd = __builtin_elementwise_fma(dz, dz, __builtin_elementwise_fma(dy, dy, dx*dx)); \
    float n0 = fminf(ds##i.x, dd.x), n1 = fminf(ds##i.y, dd.y); \
    ds##i = (v2f){n0, n1}; \
    unsigned long long c0 = ((unsigned long long)__float_as_uint(n0) << 32) | (unsigned)~(tid + (2*(i))*T); \
    unsigned long long c1 = ((unsigned long long)__float_as_uint(n1) << 32) | (unsigned)~(tid + (2*(i)+1)*T); \
    bp = c0 > bp ? c0 : bp; bp = c1 > bp ? c1 : bp; }

// ---------------- k_fps16 (level 0: 4096 -> 1024, writes nxyz) ----------------
__global__ void __launch_bounds__(256, 1)
k_fps16(const float* __restrict__ xyz, int* __restrict__ sidx, float* __restrict__ nxyz){
    constexpr int N = 4096, NPOINT = 1024, T = 256;
    const int b = blockIdx.x;
    const float* X = xyz + (size_t)b * 3 * N;
    float* NX = nxyz + (size_t)b * 3 * NPOINT;
    int tid = threadIdx.x;
    RPT8(FPS_DECL) RPT8(FPS_LOAD) RPT8(FPS_PIN)
    __shared__ float4 sxyz[N];
    __shared__ unsigned long long sred[2][4];
    for (int t = tid; t < N; t += T)
        sxyz[t] = make_float4(X[t], X[N+t], X[2*N+t], 0.f);
    if (tid == 0){ sidx[(size_t)b * NPOINT] = 0;
        NX[0] = X[0]; NX[NPOINT] = X[N]; NX[2*NPOINT] = X[2*N]; }
    v2f l2x = (v2f){X[0], X[0]}, l2y = (v2f){X[N], X[N]}, l2z = (v2f){X[2*N], X[2*N]};
    __syncthreads();
    for (int i = 1; i < NPOINT; ++i){
        unsigned long long bp = 0;
        RPT8(FPS_UPD)
        DPP_REDUCE2(bp)
        int buf = i & 1;
        if ((tid & 63) == 63) sred[buf][tid >> 6] = bp;
        __syncthreads();
        unsigned long long pp = sred[buf][0];
        #pragma unroll
        for (int k = 1; k < 4; ++k){ unsigned long long pk = sred[buf][k]; pp = pk > pp ? pk : pp; }
        int i0 = (int)~(unsigned)pp;
        float4 wn = sxyz[i0];
        l2x = (v2f){wn.x, wn.x}; l2y = (v2f){wn.y, wn.y}; l2z = (v2f){wn.z, wn.z};
        if (tid == 0){ sidx[(size_t)b * NPOINT + i] = i0;
            NX[i] = wn.x; NX[NPOINT + i] = wn.y; NX[2*NPOINT + i] = wn.z; }
    }
}

// ---------------- max-pool over k neighbors, point-major in, dual-write out ----------------
__global__ void __launch_bounds__(256, 1)
k_pool_max_pm(const float* __restrict__ pm, const int* __restrict__ idx,
              float* __restrict__ out, float* __restrict__ pmo, int np, int nsrc){
    __shared__ float tile[64][65];
    int b = blockIdx.y;
    int m0 = blockIdx.x * 64;
    int lane = threadIdx.x & 63;
    int w = threadIdx.x >> 6;
    const float* PM = pm + (size_t)b * nsrc * 64;
    float* PMO = pmo + (size_t)b * np * 64;
    const int* ID = idx + ((size_t)b * np + m0) * 8;
    for (int c = 0; c < 16; ++c){
        int ml = w * 16 + c;
        const int* id = ID + ml * 8;
        float v = -FLT_MAX;
        #pragma unroll
        for (int k = 0; k < 8; ++k)
            v = fmaxf(v, PM[(size_t)id[k] * 64 + lane]);
        tile[ml][lane] = v;
        PMO[(size_t)(m0 + ml) * 64 + lane] = v;
    }
    __syncthreads();
    float* O = out + (size_t)b * 64 * np + m0;
    for (int c = 0; c < 16; ++c){
        int d = w * 16 + c;
        O[(size_t)d * np + lane] = tile[lane][d];
    }
}

// ---------------- FUSED gather_sum + dual GEMM + epilogue, dual-write dm+pm ----------------
#define RC_DECL(i) float a##i = 0.f;
#define RC_FMA(i)  a##i = fmaf(wc[i], h, fmaf(wg[i], sv, a##i));
#define RC_FIN(i)  a##i = a##i * inv + Pr[(size_t)(i) * n];
#define RC_ST(i)   O[(size_t)(i) * n] = a##i;
#define RC_STPM(i) PO[i] = a##i;

__global__ void __launch_bounds__(256, 1)
k_res_fused(const float* __restrict__ pts, const float* __restrict__ pm,
            const int* __restrict__ idx,
            const float* __restrict__ wcT, const float* __restrict__ wgT,
            float* __restrict__ out, float* __restrict__ pmo, int n){
    __shared__ float tile[64][65];
    int b = blockIdx.y;
    int j0 = blockIdx.x * 64;
    int lane = threadIdx.x & 63;
    int w = threadIdx.x >> 6;
    const float* PM = pm + (size_t)b * n * 64;
    const int* ID = idx + ((size_t)b * n + j0) * 8;
    for (int c = 0; c < 16; ++c){
        int jl = w * 16 + c;
        const int* id = ID + jl * 8;
        float v = 0.f;
        #pragma unroll
        for (int k = 0; k < 8; ++k)
            v += leaky(PM[(size_t)id[k] * 64 + lane]);
        tile[jl][lane] = v;
    }
    __syncthreads();
    int j = j0 + lane;
    const float* P = pts + (size_t)b * 64 * n + j;
    const float* sc = &tile[lane][0];
    RPT16(RC_DECL)
    for (int d = 0; d < 64; ++d){
        float h  = leaky(P[(size_t)d * n]);
        float sv = sc[d];
        const float* wc = wcT + d * 64 + w * 16;
        const float* wg = wgT + d * 64 + w * 16;
        RPT16(RC_FMA)
    }
    const float inv = 1.0f / 9.0f;
    const float* Pr = P + (size_t)(w * 16) * n;
    RPT16(RC_FIN)
    float* O = out + ((size_t)b * 64 + w * 16) * n + j;
    RPT16(RC_ST)
    float* PO = pmo + ((size_t)b * n + j) * 64 + w * 16;
    RPT16(RC_STPM)
}

// ---------------- in-LDS res block for the tail megakernel ----------------
// pmX: [COLS][65] features (in-place updated), S: [COLS][65] scratch.
// Per tile of 64 cols: all reads (h, sv, shortcut) -> barrier -> writes -> barrier.
#define RC_FINL(i) a##i = a##i * inv + pmX[j][w * 16 + (i)];
#define RC_WLDS(i) pmX[j][w * 16 + (i)] = a##i;

__device__ __forceinline__ void res_lds(float (*pmX)[65], float (*S)[65],
        const int (*idl)[8], const float* __restrict__ wcT, const float* __restrict__ wgT,
        int lane, int w, int COLS){
    int cpw = COLS >> 2;
    for (int c = 0; c < cpw; ++c){
        int col = w * cpw + c;
        const int* id = idl[col];
        float v = 0.f;
        #pragma unroll
        for (int k = 0; k < 8; ++k) v += leaky(pmX[id[k]][lane]);
        S[col][lane] = v;
    }
    __syncthreads();
    const float inv = 1.0f / 9.0f;
    for (int t = 0; t < (COLS >> 6); ++t){
        int j = (t << 6) + lane;
        RPT16(RC_DECL)
        for (int d = 0; d < 64; ++d){
            float h  = leaky(pmX[j][d]);
            float sv = S[j][d];
            const float* wc = wcT + d * 64 + w * 16;
            const float* wg = wgT + d * 64 + w * 16;
            RPT16(RC_FMA)
        }
        RPT16(RC_FINL)
        __syncthreads();
        RPT16(RC_WLDS)
        __syncthreads();
    }
}

// ---------------- TAIL MEGAKERNEL: levels n=256 and n=64 + final, 1 block/batch ----------------
__global__ void __launch_bounds__(256, 1)
k_tail(const float* __restrict__ pm1024, const float* __restrict__ xyz1024,
       const float* __restrict__ wT, const float* __restrict__ wl,
       float* __restrict__ out){
    __shared__ float pmT[256][65];                 // 66,560 B  features @256
    __shared__ __align__(16) char regB[66560];     // 66,560 B  sx1024 -> S256 -> pm64+S64
    __shared__ int idxL[256][8];                   //  8,192 B
    __shared__ float4 sx256[256];                  //  4,096 B
    __shared__ float4 sx64[64];                    //  1,024 B
    __shared__ unsigned long long sred[2][4];

    int b = blockIdx.x, tid = threadIdx.x;
    int lane = tid & 63, w = tid >> 6;
    const float* X = xyz1024 + (size_t)b * 3 * 1024;

    // stage xyz@1024 (with |r|^2 in .w, same expression as k_knn staging)
    float4* sx1024 = (float4*)regB;
    for (int t = tid; t < 1024; t += 256){
        float rx = X[t], ry = X[1024 + t], rz = X[2048 + t];
        sx1024[t] = make_float4(rx, ry, rz, rx*rx + ry*ry + rz*rz);
    }
    __syncthreads();

    // ---- fps4: 1024 -> 256 (multi-wave, 4 pts/thread as 2 v2f)
    {
        constexpr int N = 1024, T = 256;
        RPT2_FPS_BODY: ;
        v2f px0, py0, pz0, ds0, px1, py1, pz1, ds1;
        { int g0 = tid, g1 = g0 + T;
          px0 = (v2f){X[g0], X[g1]}; py0 = (v2f){X[N+g0], X[N+g1]};
          pz0 = (v2f){X[2*N+g0], X[2*N+g1]}; ds0 = (v2f){1e10f, 1e10f}; }
        { int g0 = tid + 2*T, g1 = g0 + T;
          px1 = (v2f){X[g0], X[g1]}; py1 = (v2f){X[N+g0], X[N+g1]};
          pz1 = (v2f){X[2*N+g0], X[2*N+g1]}; ds1 = (v2f){1e10f, 1e10f}; }
        asm volatile("" : "+v"(px0), "+v"(py0), "+v"(pz0));
        asm volatile("" : "+v"(px1), "+v"(py1), "+v"(pz1));
        if (tid == 0) sx256[0] = sx1024[0];
        v2f l2x = (v2f){X[0], X[0]}, l2y = (v2f){X[N], X[N]}, l2z = (v2f){X[2*N], X[2*N]};
        for (int i = 1; i < 256; ++i){
            unsigned long long bp = 0;
            { v2f dx = px0 - l2x, dy = py0 - l2y, dz = pz0 - l2z;
              v2f dd = __builtin_elementwise_fma(dz, dz, __builtin_elementwise_fma(dy, dy, dx*dx));
              float n0 = fminf(ds0.x, dd.x), n1 = fminf(ds0.y, dd.y);
              ds0 = (v2f){n0, n1};
              unsigned long long c0 = ((unsigned long long)__float_as_uint(n0) << 32) | (unsigned)~(tid);
              unsigned long long c1 = ((unsigned long long)__float_as_uint(n1) << 32) | (unsigned)~(tid + T);
              bp = c0 > bp ? c0 : bp; bp = c1 > bp ? c1 : bp; }
            { v2f dx = px1 - l2x, dy = py1 - l2y, dz = pz1 - l2z;
              v2f dd = __builtin_elementwise_fma(dz, dz, __builtin_elementwise_fma(dy, dy, dx*dx));
              float n0 = fminf(ds1.x, dd.x), n1 = fminf(ds1.y, dd.y);
              ds1 = (v2f){n0, n1};
              unsigned long long c0 = ((unsigned long long)__float_as_uint(n0) << 32) | (unsigned)~(tid + 2*T);
              unsigned long long c1 = ((unsigned long long)__float_as_uint(n1) << 32) | (unsigned)~(tid + 3*T);
              bp = c0 > bp ? c0 : bp; bp = c1 > bp ? c1 : bp; }
            DPP_REDUCE2(bp)
            int buf = i & 1;
            if ((tid & 63) == 63) sred[buf][w] = bp;
            __syncthreads();
            unsigned long long pp = sred[buf][0];
            #pragma unroll
            for (int k = 1; k < 4; ++k){ unsigned long long pk = sred[buf][k]; pp = pk > pp ? pk : pp; }
            int i0 = (int)~(unsigned)pp;
            float4 wn = sx1024[i0];
            l2x = (v2f){wn.x, wn.x}; l2y = (v2f){wn.y, wn.y}; l2z = (v2f){wn.z, wn.z};
            if (tid == 0) sx256[i] = wn;
        }
    }
    __syncthreads();

    // ---- knn(256 new pts, 1024 refs)
    { float4 qv = sx256[tid]; KNN8(sx1024, 1024, qv, idxL[tid]) }
    __syncthreads();

    // ---- pool@256: gather max from global pm@1024
    {
        const float* PMg = pm1024 + (size_t)b * 1024 * 64;
        for (int c = 0; c < 64; ++c){
            int col = w * 64 + c;
            const int* id = idxL[col];
            float v = -FLT_MAX;
            #pragma unroll
            for (int k = 0; k < 8; ++k)
                v = fmaxf(v, PMg[(size_t)id[k] * 64 + lane]);
            pmT[col][lane] = v;
        }
    }
    __syncthreads();

    // ---- knn(256,256)
    { float4 qv = sx256[tid]; KNN8(sx256, 256, qv, idxL[tid]) }
    __syncthreads();

    // ---- 4x res@256 (in-place in pmT; S in regB)
    {
        float (*S)[65] = (float (*)[65])regB;
        for (int L = 0; L < 4; ++L)
            res_lds(pmT, S, idxL, wT + (size_t)(8 + L) * 4096,
                    wT + (size_t)(20 + L) * 4096, lane, w, 256);
    }

    // ---- fps1: 256 -> 64 (multi-wave, 1 pt/thread)
    {
        float px = sx256[tid].x, py = sx256[tid].y, pz = sx256[tid].z, ds = 1e10f;
        asm volatile("" : "+v"(px), "+v"(py), "+v"(pz));
        if (tid == 0) sx64[0] = sx256[0];
        float lx = sx256[0].x, ly = sx256[0].y, lz = sx256[0].z;
        for (int i = 1; i < 64; ++i){
            float dx = px - lx, dy = py - ly, dz = pz - lz;
            float dd = fmaf(dz, dz, fmaf(dy, dy, dx*dx));
            float nd = fminf(ds, dd); ds = nd;
            unsigned long long bp = ((unsigned long long)__float_as_uint(nd) << 32) | (unsigned)~tid;
            DPP_REDUCE2(bp)
            int buf = i & 1;
            if ((tid & 63) == 63) sred[buf][w] = bp;
            __syncthreads();
            unsigned long long pp = sred[buf][0];
            #pragma unroll
            for (int k = 1; k < 4; ++k){ unsigned long long pk = sred[buf][k]; pp = pk > pp ? pk : pp; }
            int i0 = (int)~(unsigned)pp;
            float4 wn = sx256[i0];
            lx = wn.x; ly = wn.y; lz = wn.z;
            if (tid == 0) sx64[i] = wn;
        }
    }
    __syncthreads();

    // ---- knn(64 new pts, 256 refs): wave 0 only
    if (tid < 64){ float4 qv = sx64[tid]; KNN8(sx256, 256, qv, idxL[tid]) }
    __syncthreads();

    // ---- pool@64: gather max from pmT (LDS)
    float (*pm64)[65] = (float (*)[65])regB;
    float (*S64)[65]  = (float (*)[65])(regB + 64 * 65 * 4);
    for (int c = 0; c < 16; ++c){
        int col = w * 16 + c;
        const int* id = idxL[col];
        float v = -FLT_MAX;
        #pragma unroll
        for (int k = 0; k < 8; ++k)
            v = fmaxf(v, pmT[id[k]][lane]);
        pm64[col][lane] = v;
    }
    __syncthreads();

    // ---- knn(64,64): wave 0 only
    if (tid < 64){ float4 qv = sx64[tid]; KNN8(sx64, 64, qv, idxL[tid]) }
    __syncthreads();

    // ---- 4x res@64 (in-place in pm64; S64 scratch)
    for (int L = 0; L < 4; ++L)
        res_lds(pm64, S64, idxL, wT + (size_t)(12 + L) * 4096,
                wT + (size_t)(24 + L) * 4096, lane, w, 64);

    // ---- final: leaky -> 1x1 conv to 1 channel
    if (tid < 64){
        float acc = 0.f;
        for (int d = 0; d < 64; ++d) acc += wl[d] * leaky(pm64[tid][d]);
        out[(size_t)b * 64 + tid] = acc;
    }
}

extern "C" void kernel_launch(void* const* d_in, const int* in_sizes, int n_in,
                              void* d_out, int out_size, void* d_ws, size_t ws_size,
                              hipStream_t stream){
    const float* xyz_in  = (const float*)d_in[0];
    const float* w0      = (const float*)d_in[1];
    const float* fn_wc   = (const float*)d_in[2];
    const float* fn_wg   = (const float*)d_in[3];
    const float* res_wc  = (const float*)d_in[4];
    const float* res_wg  = (const float*)d_in[5];
    const float* w_last  = (const float*)d_in[6];
    float* out = (float*)d_out;

    char* ws = (char*)d_ws;
    size_t off = 0;
    auto alloc = [&](size_t bytes) -> char* {
        char* p = ws + off;
        off = (off + bytes + 255) & ~(size_t)255;
        return p;
    };
    float* wT_all = (float*)alloc(28UL * 4096 * 4);   // [fnc0,fnc1,fng0,fng1,rc*12,rg*12]
    float* pts_a  = (float*)alloc(8UL * 64 * 4096 * 4);
    float* pts_b  = (float*)alloc(8UL * 64 * 4096 * 4);
    float* pm_a   = (float*)alloc(8UL * 64 * 4096 * 4);
    float* pm_b   = (float*)alloc(8UL * 64 * 4096 * 4);
    int*   idx_b  = (int*)  alloc(8UL * 4096 * 8 * 4);
    float* xyz1   = (float*)alloc(8UL * 3 * 1024 * 4);
    int*   sidx   = (int*)  alloc(8UL * 1024 * 4);

    k_transpose_all<<<28, 256, 0, stream>>>(fn_wc, fn_wg, res_wc, res_wg, wT_all);

    int n = 4096;
    {
        dim3 g(n / 64, 8);
        k_conv0<<<g, 256, 0, stream>>>(xyz_in, w0, pts_a, pm_a, n);
    }
    {
        dim3 kb((n + BKNN - 1) / BKNN, 8);
        k_knn<<<kb, BKNN, 0, stream>>>(xyz_in, xyz_in, n, n, idx_b);
    }
    float* pc = pts_a; float* pn = pts_b;
    float* pmc = pm_a; float* pmn = pm_b;
    for (int j = 0; j < 2; ++j){
        dim3 g(n / 64, 8);
        k_res_fused<<<g, 256, 0, stream>>>(pc, pmc, idx_b, wT_all + j * 4096,
                                           wT_all + (2 + j) * 4096, pn, pmn, n);
        float* t = pc; pc = pn; pn = t;
        t = pmc; pmc = pmn; pmn = t;
    }

    // ---- level 0: 4096 -> 1024 (existing kernels)
    k_fps16<<<8, 256, 0, stream>>>(xyz_in, sidx, xyz1);
    {
        dim3 kg((1024 + BKNN - 1) / BKNN, 8);
        k_knn<<<kg, BKNN, 0, stream>>>(xyz1, xyz_in, 1024, 4096, idx_b);
    }
    {
        dim3 pp(1024 / 64, 8);
        k_pool_max_pm<<<pp, 256, 0, stream>>>(pmc, idx_b, pn, pmn, 1024, 4096);
        float* t = pc; pc = pn; pn = t;
        t = pmc; pmc = pmn; pmn = t;
    }
    n = 1024;
    {
        dim3 ks((n + BKNN - 1) / BKNN, 8);
        k_knn<<<ks, BKNN, 0, stream>>>(xyz1, xyz1, n, n, idx_b);
    }
    for (int i = 0; i < 4; ++i){
        dim3 g(n / 64, 8);
        k_res_fused<<<g, 256, 0, stream>>>(pc, pmc, idx_b, wT_all + (4 + i) * 4096,
                                           wT_all + (16 + i) * 4096, pn, pmn, n);
        float* t = pc; pc = pn; pn = t;
        t = pmc; pmc = pmn; pmn = t;
    }

    // ---- levels n=256, n=64 and final: one megakernel, one block per batch
    k_tail<<<8, 256, 0, stream>>>(pmc, xyz1, wT_all, w_last, out);
}

// Round 13
// 2173.358 us; speedup vs baseline: 1.0819x; 1.0819x over previous
//
#include <hip/hip_runtime.h>
#include <hip/hip_bf16.h>
#include <float.h>

#define NEG_SLOPE 0.01f

typedef float v2f __attribute__((ext_vector_type(2)));

__device__ __forceinline__ float leaky(float x){ return x >= 0.0f ? x : NEG_SLOPE * x; }

#if !__has_builtin(__builtin_elementwise_fma)
#error "need __builtin_elementwise_fma"
#endif

#define RPT16(M) M(0) M(1) M(2) M(3) M(4) M(5) M(6) M(7) \
                 M(8) M(9) M(10) M(11) M(12) M(13) M(14) M(15)
#define RPT8(M) M(0) M(1) M(2) M(3) M(4) M(5) M(6) M(7)

// ---------------- all 28 weight matrices [o][d] -> [d][o], one launch ----------------
// dst layout: [0,1]=fn_wc, [2,3]=fn_wg, [4..15]=res_wc, [16..27]=res_wg
__global__ void k_transpose_all(const float* __restrict__ a, const float* __restrict__ b2,
                                const float* __restrict__ c, const float* __restrict__ d,
                                float* __restrict__ dst){
    int m = blockIdx.x;
    const float* s;
    if (m < 2) s = a + (size_t)m * 4096;
    else if (m < 4) s = b2 + (size_t)(m - 2) * 4096;
    else if (m < 16) s = c + (size_t)(m - 4) * 4096;
    else s = d + (size_t)(m - 16) * 4096;
    float* o = dst + (size_t)m * 4096;
    for (int t = threadIdx.x; t < 4096; t += blockDim.x){
        int oo = t >> 6, dd = t & 63;
        o[dd * 64 + oo] = s[t];
    }
}

// ---------------- first conv 3->64, dual-write dm + pm ----------------
__global__ void __launch_bounds__(256, 1)
k_conv0(const float* __restrict__ xyz, const float* __restrict__ w0,
        float* __restrict__ dm, float* __restrict__ pm, int n){
    int b = blockIdx.y;
    int lane = threadIdx.x & 63;
    int w = threadIdx.x >> 6;
    int j = blockIdx.x * 64 + lane;
    const float* X = xyz + (size_t)b * 3 * n;
    float x = X[j], y = X[n + j], z = X[2 * n + j];
    float* PO = pm + ((size_t)b * n + j) * 64 + w * 16;
    #pragma unroll
    for (int c = 0; c < 16; ++c){
        int oo = w * 16 + c;
        float v = w0[oo*3] * x + w0[oo*3+1] * y + w0[oo*3+2] * z;
        dm[((size_t)b * 64 + oo) * n + j] = v;
        PO[c] = v;
    }
}

// ---------------- kNN helpers ----------------
#define KNN_CHUNK 1024
#define BKNN 256

#define KNN_INS(bdX, biX) { bool c = cd < bdX; float tf = bdX; int ti = biX; \
    bdX = c ? cd : bdX; biX = c ? ci : biX; cd = c ? tf : cd; ci = c ? ti : ci; }

#define KNN_PROC(r, jj) { \
    float dot = qx * r.x + qy * r.y + qz * r.z; \
    float dcur = qq + r.w - 2.0f * dot; \
    if (dcur < bd7){ \
        float cd = dcur; int ci = (jj); \
        KNN_INS(bd0, bi0); KNN_INS(bd1, bi1); KNN_INS(bd2, bi2); KNN_INS(bd3, bi3); \
        KNN_INS(bd4, bi4); KNN_INS(bd5, bi5); KNN_INS(bd6, bi6); KNN_INS(bd7, bi7); \
    } }

// top-8 over an LDS float4 array (r.w = |r|^2); 4x unrolled (batched loads) --
// r12 post-mortem: serial loop exposed ds_read latency at 1 wave/SIMD.
// Ascending j + strict '<' tie-break (matches lax.top_k). NR % 4 == 0 always.
#define KNN8(REFS, NR, QV, OROW) { \
    float qx = (QV).x, qy = (QV).y, qz = (QV).z; \
    float qq = qx*qx + qy*qy + qz*qz; \
    float bd0=FLT_MAX,bd1=FLT_MAX,bd2=FLT_MAX,bd3=FLT_MAX; \
    float bd4=FLT_MAX,bd5=FLT_MAX,bd6=FLT_MAX,bd7=FLT_MAX; \
    int bi0=0,bi1=0,bi2=0,bi3=0,bi4=0,bi5=0,bi6=0,bi7=0; \
    for (int j_ = 0; j_ < (NR); j_ += 4){ \
        float4 r0 = (REFS)[j_];   float4 r1 = (REFS)[j_+1]; \
        float4 r2 = (REFS)[j_+2]; float4 r3 = (REFS)[j_+3]; \
        KNN_PROC(r0, j_) KNN_PROC(r1, j_+1) KNN_PROC(r2, j_+2) KNN_PROC(r3, j_+3) \
    } \
    (OROW)[0]=bi0; (OROW)[1]=bi1; (OROW)[2]=bi2; (OROW)[3]=bi3; \
    (OROW)[4]=bi4; (OROW)[5]=bi5; (OROW)[6]=bi6; (OROW)[7]=bi7; }

__global__ void __launch_bounds__(BKNN, 2)
k_knn(const float* __restrict__ q, const float* __restrict__ ref,
      int M, int Nr, int* __restrict__ idx_out){
    __shared__ float4 sref[KNN_CHUNK];
    int b = blockIdx.y;
    int m = blockIdx.x * BKNN + threadIdx.x;
    const float* Q = q + (size_t)b * 3 * M;
    const float* R = ref + (size_t)b * 3 * Nr;
    bool valid = (m < M);
    float qx = 0.f, qy = 0.f, qz = 0.f, qq = 0.f;
    if (valid){
        qx = Q[m]; qy = Q[M + m]; qz = Q[2 * M + m];
        qq = qx*qx + qy*qy + qz*qz;
    }
    float bd0 = FLT_MAX, bd1 = FLT_MAX, bd2 = FLT_MAX, bd3 = FLT_MAX;
    float bd4 = FLT_MAX, bd5 = FLT_MAX, bd6 = FLT_MAX, bd7 = FLT_MAX;
    int bi0 = 0, bi1 = 0, bi2 = 0, bi3 = 0, bi4 = 0, bi5 = 0, bi6 = 0, bi7 = 0;

    for (int base = 0; base < Nr; base += KNN_CHUNK){
        int jmax = min(KNN_CHUNK, Nr - base);
        for (int j = threadIdx.x; j < jmax; j += BKNN){
            float rx = R[base + j], ry = R[Nr + base + j], rz = R[2 * Nr + base + j];
            sref[j] = make_float4(rx, ry, rz, rx*rx + ry*ry + rz*rz);
        }
        __syncthreads();
        for (int j = 0; j < jmax; j += 4){
            float4 r0 = sref[j+0]; float4 r1 = sref[j+1];
            float4 r2 = sref[j+2]; float4 r3 = sref[j+3];
            KNN_PROC(r0, base + j + 0)
            KNN_PROC(r1, base + j + 1)
            KNN_PROC(r2, base + j + 2)
            KNN_PROC(r3, base + j + 3)
        }
        __syncthreads();
    }
    if (valid){
        int* o = idx_out + ((size_t)b * M + m) * 8;
        o[0] = bi0; o[1] = bi1; o[2] = bi2; o[3] = bi3;
        o[4] = bi4; o[5] = bi5; o[6] = bi6; o[7] = bi7;
    }
}

// ---------------- FPS primitives ----------------
template<int CTRL>
__device__ __forceinline__ void dpp2(unsigned long long &bp){
    unsigned h = (unsigned)(bp >> 32), l = (unsigned)bp;
    unsigned th = (unsigned)__builtin_amdgcn_update_dpp(0, (int)h, CTRL, 0xF, 0xF, true);
    unsigned tl = (unsigned)__builtin_amdgcn_update_dpp(0, (int)l, CTRL, 0xF, 0xF, true);
    unsigned long long tp = ((unsigned long long)th << 32) | tl;
    bp = tp > bp ? tp : bp;
}
#define DPP_REDUCE2(bp) dpp2<0x111>(bp); dpp2<0x112>(bp); dpp2<0x114>(bp); \
    dpp2<0x118>(bp); dpp2<0x142>(bp); dpp2<0x143>(bp);

#define FPS_DECL(i) v2f px##i, py##i, pz##i, ds##i;
#define FPS_LOAD(i) { int g0 = tid + (2*(i))*T, g1 = g0 + T; \
    px##i = (v2f){X[g0], X[g1]}; py##i = (v2f){X[N+g0], X[N+g1]}; \
    pz##i = (v2f){X[2*N+g0], X[2*N+g1]}; ds##i = (v2f){1e10f, 1e10f}; }
#define FPS_PIN(i) asm volatile("" : "+v"(px##i), "+v"(py##i), "+v"(pz##i));
// dist >= 0 => float bit order == value order; ~gi larger => gi smaller, so
// u64 max == (dist >, tie: idx <) exactly.
#define FPS_UPD(i) { \
    v2f dx = px##i - l2x, dy = py##i - l2y, dz = pz##i - l2z; \
    v2f dd = __builtin_elementwise_fma(dz, dz, __builtin_elementwise_fma(dy, dy, dx*dx)); \
    float n0 = fminf(ds##i.x, dd.x), n1 = fminf(ds##i.y, dd.y); \
    ds##i = (v2f){n0, n1}; \
    unsigned long long c0 = ((unsigned long long)__float_as_uint(n0) << 32) | (unsigned)~(tid + (2*(i))*T); \
    unsigned long long c1 = ((unsigned long long)__float_as_uint(n1) << 32) | (unsigned)~(tid + (2*(i)+1)*T); \
    bp = c0 > bp ? c0 : bp; bp = c1 > bp ? c1 : bp; }

// ---------------- k_fps16 (level 0: 4096 -> 1024, writes nxyz) ----------------
__global__ void __launch_bounds__(256, 1)
k_fps16(const float* __restrict__ xyz, int* __restrict__ sidx, float* __restrict__ nxyz){
    constexpr int N = 4096, NPOINT = 1024, T = 256;
    const int b = blockIdx.x;
    const float* X = xyz + (size_t)b * 3 * N;
    float* NX = nxyz + (size_t)b * 3 * NPOINT;
    int tid = threadIdx.x;
    RPT8(FPS_DECL) RPT8(FPS_LOAD) RPT8(FPS_PIN)
    __shared__ float4 sxyz[N];
    __shared__ unsigned long long sred[2][4];
    for (int t = tid; t < N; t += T)
        sxyz[t] = make_float4(X[t], X[N+t], X[2*N+t], 0.f);
    if (tid == 0){ sidx[(size_t)b * NPOINT] = 0;
        NX[0] = X[0]; NX[NPOINT] = X[N]; NX[2*NPOINT] = X[2*N]; }
    v2f l2x = (v2f){X[0], X[0]}, l2y = (v2f){X[N], X[N]}, l2z = (v2f){X[2*N], X[2*N]};
    __syncthreads();
    for (int i = 1; i < NPOINT; ++i){
        unsigned long long bp = 0;
        RPT8(FPS_UPD)
        DPP_REDUCE2(bp)
        int buf = i & 1;
        if ((tid & 63) == 63) sred[buf][tid >> 6] = bp;
        __syncthreads();
        unsigned long long pp = sred[buf][0];
        #pragma unroll
        for (int k = 1; k < 4; ++k){ unsigned long long pk = sred[buf][k]; pp = pk > pp ? pk : pp; }
        int i0 = (int)~(unsigned)pp;
        float4 wn = sxyz[i0];
        l2x = (v2f){wn.x, wn.x}; l2y = (v2f){wn.y, wn.y}; l2z = (v2f){wn.z, wn.z};
        if (tid == 0){ sidx[(size_t)b * NPOINT + i] = i0;
            NX[i] = wn.x; NX[NPOINT + i] = wn.y; NX[2*NPOINT + i] = wn.z; }
    }
}

// ---------------- max-pool over k neighbors, point-major in, dual-write out ----------------
__global__ void __launch_bounds__(256, 1)
k_pool_max_pm(const float* __restrict__ pm, const int* __restrict__ idx,
              float* __restrict__ out, float* __restrict__ pmo, int np, int nsrc){
    __shared__ float tile[64][65];
    int b = blockIdx.y;
    int m0 = blockIdx.x * 64;
    int lane = threadIdx.x & 63;
    int w = threadIdx.x >> 6;
    const float* PM = pm + (size_t)b * nsrc * 64;
    float* PMO = pmo + (size_t)b * np * 64;
    const int* ID = idx + ((size_t)b * np + m0) * 8;
    for (int c = 0; c < 16; ++c){
        int ml = w * 16 + c;
        const int* id = ID + ml * 8;
        float v = -FLT_MAX;
        #pragma unroll
        for (int k = 0; k < 8; ++k)
            v = fmaxf(v, PM[(size_t)id[k] * 64 + lane]);
        tile[ml][lane] = v;
        PMO[(size_t)(m0 + ml) * 64 + lane] = v;
    }
    __syncthreads();
    float* O = out + (size_t)b * 64 * np + m0;
    for (int c = 0; c < 16; ++c){
        int d = w * 16 + c;
        O[(size_t)d * np + lane] = tile[lane][d];
    }
}

// ---------------- FUSED gather_sum + dual GEMM + epilogue, dual-write dm+pm ----------------
#define RC_DECL(i) float a##i = 0.f;
#define RC_FMA(i)  a##i = fmaf(wc[i], h, fmaf(wg[i], sv, a##i));
#define RC_FIN(i)  a##i = a##i * inv + Pr[(size_t)(i) * n];
#define RC_ST(i)   O[(size_t)(i) * n] = a##i;
#define RC_STPM(i) PO[i] = a##i;

__global__ void __launch_bounds__(256, 1)
k_res_fused(const float* __restrict__ pts, const float* __restrict__ pm,
            const int* __restrict__ idx,
            const float* __restrict__ wcT, const float* __restrict__ wgT,
            float* __restrict__ out, float* __restrict__ pmo, int n){
    __shared__ float tile[64][65];
    int b = blockIdx.y;
    int j0 = blockIdx.x * 64;
    int lane = threadIdx.x & 63;
    int w = threadIdx.x >> 6;
    const float* PM = pm + (size_t)b * n * 64;
    const int* ID = idx + ((size_t)b * n + j0) * 8;
    for (int c = 0; c < 16; ++c){
        int jl = w * 16 + c;
        const int* id = ID + jl * 8;
        float v = 0.f;
        #pragma unroll
        for (int k = 0; k < 8; ++k)
            v += leaky(PM[(size_t)id[k] * 64 + lane]);
        tile[jl][lane] = v;
    }
    __syncthreads();
    int j = j0 + lane;
    const float* P = pts + (size_t)b * 64 * n + j;
    const float* sc = &tile[lane][0];
    RPT16(RC_DECL)
    for (int d = 0; d < 64; ++d){
        float h  = leaky(P[(size_t)d * n]);
        float sv = sc[d];
        const float* wc = wcT + d * 64 + w * 16;
        const float* wg = wgT + d * 64 + w * 16;
        RPT16(RC_FMA)
    }
    const float inv = 1.0f / 9.0f;
    const float* Pr = P + (size_t)(w * 16) * n;
    RPT16(RC_FIN)
    float* O = out + ((size_t)b * 64 + w * 16) * n + j;
    RPT16(RC_ST)
    float* PO = pmo + ((size_t)b * n + j) * 64 + w * 16;
    RPT16(RC_STPM)
}

// ---------------- in-LDS res blocks for the tail megakernel ----------------
// COLS=256: loop-interchanged — 64 named accumulators (4 col-tiles x 16 outs)
// so one wave-uniform s_load of wc/wg per d feeds 128 FMAs (latency amortized,
// 4-way ILP). Per-output d-order and fma chain identical to k_res_fused.
#define RC4_DECL(i) float aA##i=0.f, aB##i=0.f, aC##i=0.f, aD##i=0.f;
#define RC4_FMA(i) { aA##i = fmaf(wc[i], hA, fmaf(wg[i], sA, aA##i)); \
                     aB##i = fmaf(wc[i], hB, fmaf(wg[i], sB, aB##i)); \
                     aC##i = fmaf(wc[i], hC, fmaf(wg[i], sC, aC##i)); \
                     aD##i = fmaf(wc[i], hD, fmaf(wg[i], sD, aD##i)); }
#define RC4_FIN(i) { aA##i = aA##i*inv + pmX[lane      ][w16+(i)]; \
                     aB##i = aB##i*inv + pmX[lane + 64 ][w16+(i)]; \
                     aC##i = aC##i*inv + pmX[lane + 128][w16+(i)]; \
                     aD##i = aD##i*inv + pmX[lane + 192][w16+(i)]; }
#define RC4_W(i)   { pmX[lane      ][w16+(i)] = aA##i; \
                     pmX[lane + 64 ][w16+(i)] = aB##i; \
                     pmX[lane + 128][w16+(i)] = aC##i; \
                     pmX[lane + 192][w16+(i)] = aD##i; }

__device__ __forceinline__ void res_lds256(float (*pmX)[65], float (*S)[65],
        const int (*idl)[8], const float* __restrict__ wcT, const float* __restrict__ wgT,
        int lane, int w){
    for (int c = 0; c < 64; ++c){
        int col = w * 64 + c;
        const int* id = idl[col];
        float v = 0.f;
        #pragma unroll
        for (int k = 0; k < 8; ++k) v += leaky(pmX[id[k]][lane]);
        S[col][lane] = v;
    }
    __syncthreads();
    int w16 = w * 16;
    RPT16(RC4_DECL)
    for (int d = 0; d < 64; ++d){
        float hA = leaky(pmX[lane      ][d]), sA = S[lane      ][d];
        float hB = leaky(pmX[lane + 64 ][d]), sB = S[lane + 64 ][d];
        float hC = leaky(pmX[lane + 128][d]), sC = S[lane + 128][d];
        float hD = leaky(pmX[lane + 192][d]), sD = S[lane + 192][d];
        const float* wc = wcT + d * 64 + w16;
        const float* wg = wgT + d * 64 + w16;
        RPT16(RC4_FMA)
    }
    const float inv = 1.0f / 9.0f;
    RPT16(RC4_FIN)
    __syncthreads();          // all reads of pmX complete
    RPT16(RC4_W)
    __syncthreads();          // writes visible
}

// COLS=64: single tile; unroll 2 lets next-d s_loads pipeline under FMAs.
#define RC_FINL64(i) a##i = a##i * inv + pmX[lane][w16 + (i)];
#define RC_WL64(i)   pmX[lane][w16 + (i)] = a##i;

__device__ __forceinline__ void res_lds64(float (*pmX)[65], float (*S)[65],
        const int (*idl)[8], const float* __restrict__ wcT, const float* __restrict__ wgT,
        int lane, int w){
    for (int c = 0; c < 16; ++c){
        int col = w * 16 + c;
        const int* id = idl[col];
        float v = 0.f;
        #pragma unroll
        for (int k = 0; k < 8; ++k) v += leaky(pmX[id[k]][lane]);
        S[col][lane] = v;
    }
    __syncthreads();
    int w16 = w * 16;
    RPT16(RC_DECL)
    #pragma unroll 2
    for (int d = 0; d < 64; ++d){
        float h  = leaky(pmX[lane][d]);
        float sv = S[lane][d];
        const float* wc = wcT + d * 64 + w16;
        const float* wg = wgT + d * 64 + w16;
        RPT16(RC_FMA)
    }
    const float inv = 1.0f / 9.0f;
    RPT16(RC_FINL64)
    __syncthreads();
    RPT16(RC_WL64)
    __syncthreads();
}

// ---------------- TAIL MEGAKERNEL: levels n=256 and n=64 + final, 1 block/batch ----------------
__global__ void __launch_bounds__(256, 1)
k_tail(const float* __restrict__ pm1024, const float* __restrict__ xyz1024,
       const float* __restrict__ wT, const float* __restrict__ wl,
       float* __restrict__ out){
    __shared__ float pmT[256][65];                 // 66,560 B  features @256
    __shared__ __align__(16) char regB[66560];     // 66,560 B  sx1024 -> S256 -> pm64+S64
    __shared__ int idxL[256][8];                   //  8,192 B
    __shared__ float4 sx256[256];                  //  4,096 B
    __shared__ float4 sx64[64];                    //  1,024 B
    __shared__ unsigned long long sred[2][4];

    int b = blockIdx.x, tid = threadIdx.x;
    int lane = tid & 63, w = tid >> 6;
    const float* X = xyz1024 + (size_t)b * 3 * 1024;

    // stage xyz@1024 (with |r|^2 in .w, same expression as k_knn staging)
    float4* sx1024 = (float4*)regB;
    for (int t = tid; t < 1024; t += 256){
        float rx = X[t], ry = X[1024 + t], rz = X[2048 + t];
        sx1024[t] = make_float4(rx, ry, rz, rx*rx + ry*ry + rz*rz);
    }
    __syncthreads();

    // ---- fps4: 1024 -> 256 (multi-wave, 4 pts/thread as 2 v2f)
    {
        constexpr int N = 1024, T = 256;
        v2f px0, py0, pz0, ds0, px1, py1, pz1, ds1;
        { int g0 = tid, g1 = g0 + T;
          px0 = (v2f){X[g0], X[g1]}; py0 = (v2f){X[N+g0], X[N+g1]};
          pz0 = (v2f){X[2*N+g0], X[2*N+g1]}; ds0 = (v2f){1e10f, 1e10f}; }
        { int g0 = tid + 2*T, g1 = g0 + T;
          px1 = (v2f){X[g0], X[g1]}; py1 = (v2f){X[N+g0], X[N+g1]};
          pz1 = (v2f){X[2*N+g0], X[2*N+g1]}; ds1 = (v2f){1e10f, 1e10f}; }
        asm volatile("" : "+v"(px0), "+v"(py0), "+v"(pz0));
        asm volatile("" : "+v"(px1), "+v"(py1), "+v"(pz1));
        if (tid == 0) sx256[0] = sx1024[0];
        v2f l2x = (v2f){X[0], X[0]}, l2y = (v2f){X[N], X[N]}, l2z = (v2f){X[2*N], X[2*N]};
        for (int i = 1; i < 256; ++i){
            unsigned long long bp = 0;
            { v2f dx = px0 - l2x, dy = py0 - l2y, dz = pz0 - l2z;
              v2f dd = __builtin_elementwise_fma(dz, dz, __builtin_elementwise_fma(dy, dy, dx*dx));
              float n0 = fminf(ds0.x, dd.x), n1 = fminf(ds0.y, dd.y);
              ds0 = (v2f){n0, n1};
              unsigned long long c0 = ((unsigned long long)__float_as_uint(n0) << 32) | (unsigned)~(tid);
              unsigned long long c1 = ((unsigned long long)__float_as_uint(n1) << 32) | (unsigned)~(tid + T);
              bp = c0 > bp ? c0 : bp; bp = c1 > bp ? c1 : bp; }
            { v2f dx = px1 - l2x, dy = py1 - l2y, dz = pz1 - l2z;
              v2f dd = __builtin_elementwise_fma(dz, dz, __builtin_elementwise_fma(dy, dy, dx*dx));
              float n0 = fminf(ds1.x, dd.x), n1 = fminf(ds1.y, dd.y);
              ds1 = (v2f){n0, n1};
              unsigned long long c0 = ((unsigned long long)__float_as_uint(n0) << 32) | (unsigned)~(tid + 2*T);
              unsigned long long c1 = ((unsigned long long)__float_as_uint(n1) << 32) | (unsigned)~(tid + 3*T);
              bp = c0 > bp ? c0 : bp; bp = c1 > bp ? c1 : bp; }
            DPP_REDUCE2(bp)
            int buf = i & 1;
            if ((tid & 63) == 63) sred[buf][w] = bp;
            __syncthreads();
            unsigned long long pp = sred[buf][0];
            #pragma unroll
            for (int k = 1; k < 4; ++k){ unsigned long long pk = sred[buf][k]; pp = pk > pp ? pk : pp; }
            int i0 = (int)~(unsigned)pp;
            float4 wn = sx1024[i0];
            l2x = (v2f){wn.x, wn.x}; l2y = (v2f){wn.y, wn.y}; l2z = (v2f){wn.z, wn.z};
            if (tid == 0) sx256[i] = wn;
        }
    }
    __syncthreads();

    // ---- knn(256 new pts, 1024 refs)
    { float4 qv = sx256[tid]; KNN8(sx1024, 1024, qv, idxL[tid]) }
    __syncthreads();

    // ---- pool@256: gather max from global pm@1024
    {
        const float* PMg = pm1024 + (size_t)b * 1024 * 64;
        for (int c = 0; c < 64; ++c){
            int col = w * 64 + c;
            const int* id = idxL[col];
            float v = -FLT_MAX;
            #pragma unroll
            for (int k = 0; k < 8; ++k)
                v = fmaxf(v, PMg[(size_t)id[k] * 64 + lane]);
            pmT[col][lane] = v;
        }
    }
    __syncthreads();

    // ---- knn(256,256)
    { float4 qv = sx256[tid]; KNN8(sx256, 256, qv, idxL[tid]) }
    __syncthreads();

    // ---- 4x res@256 (in-place in pmT; S in regB)
    {
        float (*S)[65] = (float (*)[65])regB;
        for (int L = 0; L < 4; ++L)
            res_lds256(pmT, S, idxL, wT + (size_t)(8 + L) * 4096,
                       wT + (size_t)(20 + L) * 4096, lane, w);
    }

    // ---- fps1: 256 -> 64 (multi-wave, 1 pt/thread)
    {
        float px = sx256[tid].x, py = sx256[tid].y, pz = sx256[tid].z, ds = 1e10f;
        asm volatile("" : "+v"(px), "+v"(py), "+v"(pz));
        if (tid == 0) sx64[0] = sx256[0];
        float lx = sx256[0].x, ly = sx256[0].y, lz = sx256[0].z;
        for (int i = 1; i < 64; ++i){
            float dx = px - lx, dy = py - ly, dz = pz - lz;
            float dd = fmaf(dz, dz, fmaf(dy, dy, dx*dx));
            float nd = fminf(ds, dd); ds = nd;
            unsigned long long bp = ((unsigned long long)__float_as_uint(nd) << 32) | (unsigned)~tid;
            DPP_REDUCE2(bp)
            int buf = i & 1;
            if ((tid & 63) == 63) sred[buf][w] = bp;
            __syncthreads();
            unsigned long long pp = sred[buf][0];
            #pragma unroll
            for (int k = 1; k < 4; ++k){ unsigned long long pk = sred[buf][k]; pp = pk > pp ? pk : pp; }
            int i0 = (int)~(unsigned)pp;
            float4 wn = sx256[i0];
            lx = wn.x; ly = wn.y; lz = wn.z;
            if (tid == 0) sx64[i] = wn;
        }
    }
    __syncthreads();

    // ---- knn(64 new pts, 256 refs): wave 0 only
    if (tid < 64){ float4 qv = sx64[tid]; KNN8(sx256, 256, qv, idxL[tid]) }
    __syncthreads();

    // ---- pool@64: gather max from pmT (LDS)
    float (*pm64)[65] = (float (*)[65])regB;
    float (*S64)[65]  = (float (*)[65])(regB + 64 * 65 * 4);
    for (int c = 0; c < 16; ++c){
        int col = w * 16 + c;
        const int* id = idxL[col];
        float v = -FLT_MAX;
        #pragma unroll
        for (int k = 0; k < 8; ++k)
            v = fmaxf(v, pmT[id[k]][lane]);
        pm64[col][lane] = v;
    }
    __syncthreads();

    // ---- knn(64,64): wave 0 only
    if (tid < 64){ float4 qv = sx64[tid]; KNN8(sx64, 64, qv, idxL[tid]) }
    __syncthreads();

    // ---- 4x res@64 (in-place in pm64; S64 scratch)
    for (int L = 0; L < 4; ++L)
        res_lds64(pm64, S64, idxL, wT + (size_t)(12 + L) * 4096,
                  wT + (size_t)(24 + L) * 4096, lane, w);

    // ---- final: leaky -> 1x1 conv to 1 channel
    if (tid < 64){
        float acc = 0.f;
        for (int d = 0; d < 64; ++d) acc += wl[d] * leaky(pm64[tid][d]);
        out[(size_t)b * 64 + tid] = acc;
    }
}

extern "C" void kernel_launch(void* const* d_in, const int* in_sizes, int n_in,
                              void* d_out, int out_size, void* d_ws, size_t ws_size,
                              hipStream_t stream){
    const float* xyz_in  = (const float*)d_in[0];
    const float* w0      = (const float*)d_in[1];
    const float* fn_wc   = (const float*)d_in[2];
    const float* fn_wg   = (const float*)d_in[3];
    const float* res_wc  = (const float*)d_in[4];
    const float* res_wg  = (const float*)d_in[5];
    const float* w_last  = (const float*)d_in[6];
    float* out = (float*)d_out;

    char* ws = (char*)d_ws;
    size_t off = 0;
    auto alloc = [&](size_t bytes) -> char* {
        char* p = ws + off;
        off = (off + bytes + 255) & ~(size_t)255;
        return p;
    };
    float* wT_all = (float*)alloc(28UL * 4096 * 4);   // [fnc0,fnc1,fng0,fng1,rc*12,rg*12]
    float* pts_a  = (float*)alloc(8UL * 64 * 4096 * 4);
    float* pts_b  = (float*)alloc(8UL * 64 * 4096 * 4);
    float* pm_a   = (float*)alloc(8UL * 64 * 4096 * 4);
    float* pm_b   = (float*)alloc(8UL * 64 * 4096 * 4);
    int*   idx_b  = (int*)  alloc(8UL * 4096 * 8 * 4);
    float* xyz1   = (float*)alloc(8UL * 3 * 1024 * 4);
    int*   sidx   = (int*)  alloc(8UL * 1024 * 4);

    k_transpose_all<<<28, 256, 0, stream>>>(fn_wc, fn_wg, res_wc, res_wg, wT_all);

    int n = 4096;
    {
        dim3 g(n / 64, 8);
        k_conv0<<<g, 256, 0, stream>>>(xyz_in, w0, pts_a, pm_a, n);
    }
    {
        dim3 kb((n + BKNN - 1) / BKNN, 8);
        k_knn<<<kb, BKNN, 0, stream>>>(xyz_in, xyz_in, n, n, idx_b);
    }
    float* pc = pts_a; float* pn = pts_b;
    float* pmc = pm_a; float* pmn = pm_b;
    for (int j = 0; j < 2; ++j){
        dim3 g(n / 64, 8);
        k_res_fused<<<g, 256, 0, stream>>>(pc, pmc, idx_b, wT_all + j * 4096,
                                           wT_all + (2 + j) * 4096, pn, pmn, n);
        float* t = pc; pc = pn; pn = t;
        t = pmc; pmc = pmn; pmn = t;
    }

    // ---- level 0: 4096 -> 1024 (existing kernels)
    k_fps16<<<8, 256, 0, stream>>>(xyz_in, sidx, xyz1);
    {
        dim3 kg((1024 + BKNN - 1) / BKNN, 8);
        k_knn<<<kg, BKNN, 0, stream>>>(xyz1, xyz_in, 1024, 4096, idx_b);
    }
    {
        dim3 pp(1024 / 64, 8);
        k_pool_max_pm<<<pp, 256, 0, stream>>>(pmc, idx_b, pn, pmn, 1024, 4096);
        float* t = pc; pc = pn; pn = t;
        t = pmc; pmc = pmn; pmn = t;
    }
    n = 1024;
    {
        dim3 ks((n + BKNN - 1) / BKNN, 8);
        k_knn<<<ks, BKNN, 0, stream>>>(xyz1, xyz1, n, n, idx_b);
    }
    for (int i = 0; i < 4; ++i){
        dim3 g(n / 64, 8);
        k_res_fused<<<g, 256, 0, stream>>>(pc, pmc, idx_b, wT_all + (4 + i) * 4096,
                                           wT_all + (16 + i) * 4096, pn, pmn, n);
        float* t = pc; pc = pn; pn = t;
        t = pmc; pmc = pmn; pmn = t;
    }

    // ---- levels n=256, n=64 and final: one megakernel, one block per batch
    k_tail<<<8, 256, 0, stream>>>(pmc, xyz1, wT_all, w_last, out);
}